// Round 1
// baseline (184.122 us; speedup 1.0000x reference)
//
#include <hip/hip_runtime.h>
#include <hip/hip_fp8.h>

#define N_IN 1024
#define N_OUT 1024
#define BATCHN 8192

typedef __attribute__((ext_vector_type(4))) int intx4;
typedef __attribute__((ext_vector_type(8))) int intx8;
typedef __attribute__((ext_vector_type(16))) float floatx16;

__device__ __forceinline__ unsigned int f2e4m3(float f) {  // OCP e4m3fn byte
  __hip_fp8_e4m3 v(f);
  return (unsigned int)v.__x;
}
// gelu ~= v * sigmoid(1.702 v) = v * rcp(1 + exp2(-2.4554 v)).
// Max abs err ~0.02 — below the fp8 e4m3 quantization noise of the GEMM path.
__device__ __forceinline__ float gelu_fast(float v) {
  float e = __builtin_amdgcn_exp2f(-2.4554443f * v);
  return v * __builtin_amdgcn_rcpf(1.0f + e);
}

// ---------------------------------------------------------------------------
// Kernel 1: tiny prep. blocks [0,1024): W rows -> fp8 e4m3 (x16 scale).
// blocks [1024,1088): slopes/intercepts [:,0,:] gather-transpose (s-major).
// ---------------------------------------------------------------------------
__global__ __launch_bounds__(256) void prep_w(const float* __restrict__ W,
                                              unsigned char* __restrict__ Wb8,
                                              const float* __restrict__ slopes,
                                              const float* __restrict__ icpts,
                                              float* __restrict__ slt,
                                              float* __restrict__ ict) {
  const int b = blockIdx.x, t = threadIdx.x;
  if (b < N_OUT) {
    float4 v = ((const float4*)(W + b * N_IN))[t];
    unsigned int pk = f2e4m3(v.x * 16.0f) | (f2e4m3(v.y * 16.0f) << 8) |
                      (f2e4m3(v.z * 16.0f) << 16) | (f2e4m3(v.w * 16.0f) << 24);
    ((unsigned int*)(Wb8 + b * N_IN))[t] = pk;
  } else {
    const int gb = b - N_OUT;  // 0..63
    const int o = gb * 16 + (t >> 4);
    const int s = t & 15;
    if (s < 9) {
      slt[s * N_OUT + o] = slopes[(long)o * 9216 + s];  // slopes[o][0][s]
      ict[s * N_OUT + o] = icpts[(long)o * 9216 + s];
    }
  }
}

// ---------------------------------------------------------------------------
// Kernel 2: fully fused. 256 blocks x 512 threads (8 waves), 1 block/CU.
// Block owns 32 rows x all 1024 cols.
//   Phase 1: wave w stages rows 4w..4w+3: gelu(x)*4 -> fp8 in LDS
//            (16B-chunk XOR swizzle, phys chunk = c ^ (row&7)) + per-row
//            segment stats (sx[9], sc[9]) into LDS.
//   Phase 2: MX-fp8 GEMM. Wave w computes cols [128w,128w+128): A frags from
//            LDS (shared by all waves), B frags DIRECT FROM GLOBAL (Wb8 is
//            1 MB -> L2-resident; no LDS staging, no barriers in K-loop).
//   Phase 3: epilogue in-block: + bias + rank-18 lin term (f32 VALU),
//            full-row LayerNorm via shfl(32-lane) + cross-wave LDS partials,
//            PReLU, nontemporal f32 stores. No Cb/g8/seg global round-trips.
// ---------------------------------------------------------------------------
__global__ __launch_bounds__(512) void fused(const float* __restrict__ x,
                                             const unsigned char* __restrict__ Wb8,
                                             const float* __restrict__ biases,
                                             const float* __restrict__ slt,
                                             const float* __restrict__ ict,
                                             const float* __restrict__ prelu_w,
                                             float* __restrict__ out) {
  __shared__ unsigned char lA[32 * 1024];   // 32 KB fp8 A tile (swizzled)
  __shared__ float seg_lds[32][24];         // sx at [0..8], sc at [12..20]
  __shared__ float2 red[8][32];             // per-wave (sum, sumsq) partials
  __shared__ float2 rowstat[32];            // (mu, rstd)

  const int t = threadIdx.x;
  const int lane = t & 63, w = t >> 6;
  const int l31 = lane & 31, lh = lane >> 5;
  const int r0 = blockIdx.x * 32;

  // ---- Phase 1: stage A + segment stats --------------------------------
  for (int jr = 0; jr < 4; ++jr) {
    const int rl = 4 * w + jr;  // local row 0..31
    const float* xr = x + (r0 + rl) * N_IN;
    unsigned int* lrow = (unsigned int*)(lA + rl * 1024);
    const int sw = rl & 7;
    float cum[8], cumx[8], totx = 0.f;
#pragma unroll
    for (int s = 0; s < 8; ++s) { cum[s] = 0.f; cumx[s] = 0.f; }
#pragma unroll
    for (int jc = 0; jc < 4; ++jc) {
      float4 v4 = ((const float4*)xr)[lane + 64 * jc];
      float vs[4] = {v4.x, v4.y, v4.z, v4.w};
      unsigned int pk = 0;
#pragma unroll
      for (int e = 0; e < 4; ++e) {
        float v = vs[e];
        pk |= f2e4m3(gelu_fast(v) * 4.0f) << (8 * e);  // x4 scale
        totx += v;
#pragma unroll
        for (int k = 0; k < 8; ++k) {
          bool m = v >= (-1.0f + (float)(k + 1) * (2.0f / 9.0f));
          cum[k] += m ? 1.0f : 0.0f;
          cumx[k] += m ? v : 0.0f;
        }
      }
      const int d = lane + 64 * jc;  // dword index within row (0..255)
      lrow[(((d >> 2) ^ sw) << 2) | (d & 3)] = pk;
    }
#pragma unroll
    for (int off = 32; off > 0; off >>= 1) {
      totx += __shfl_xor(totx, off);
#pragma unroll
      for (int s = 0; s < 8; ++s) {
        cum[s] += __shfl_xor(cum[s], off);
        cumx[s] += __shfl_xor(cumx[s], off);
      }
    }
    if (lane == 0) {
      seg_lds[rl][0] = totx - cumx[0];
      seg_lds[rl][12] = 1024.f - cum[0];
#pragma unroll
      for (int s = 1; s < 8; ++s) {
        seg_lds[rl][s] = cumx[s - 1] - cumx[s];
        seg_lds[rl][12 + s] = cum[s - 1] - cum[s];
      }
      seg_lds[rl][8] = cumx[7];
      seg_lds[rl][20] = cum[7];
    }
  }
  __syncthreads();

  // ---- Phase 2: GEMM, B direct from L2 ---------------------------------
  const int nb = w * 128;
  floatx16 acc[4] = {};
  const unsigned char* aRow = lA + l31 * 1024;
  const int asw = l31 & 7;
  const unsigned char* bp0 = Wb8 + (nb + l31) * N_IN + lh * 32;

#define LOAD_A(ko, AF)                                                         \
  {                                                                            \
    const int c0 = ((ko) >> 4) + lh * 2;                                       \
    intx4 lo = *(const intx4*)(aRow + ((c0 ^ asw) << 4));                      \
    intx4 hi = *(const intx4*)(aRow + (((c0 + 1) ^ asw) << 4));                \
    AF[0] = lo[0]; AF[1] = lo[1]; AF[2] = lo[2]; AF[3] = lo[3];                \
    AF[4] = hi[0]; AF[5] = hi[1]; AF[6] = hi[2]; AF[7] = hi[3];                \
  }
#define LOAD_B(ko, ni, BF)                                                     \
  {                                                                            \
    const unsigned char* bp = bp0 + (ni) * 32 * N_IN + (ko);                   \
    intx4 lo = *(const intx4*)bp;                                              \
    intx4 hi = *(const intx4*)(bp + 16);                                       \
    BF[0] = lo[0]; BF[1] = lo[1]; BF[2] = lo[2]; BF[3] = lo[3];                \
    BF[4] = hi[0]; BF[5] = hi[1]; BF[6] = hi[2]; BF[7] = hi[3];                \
  }

  for (int kt = 0; kt < 16; kt += 2) {  // pair-unrolled: loads lead MFMAs
    intx8 a0, a1, b0[4], b1[4];
    LOAD_A(kt * 64, a0);
    LOAD_A(kt * 64 + 64, a1);
#pragma unroll
    for (int ni = 0; ni < 4; ++ni) LOAD_B(kt * 64, ni, b0[ni]);
#pragma unroll
    for (int ni = 0; ni < 4; ++ni) LOAD_B(kt * 64 + 64, ni, b1[ni]);
#pragma unroll
    for (int ni = 0; ni < 4; ++ni)
      acc[ni] = __builtin_amdgcn_mfma_scale_f32_32x32x64_f8f6f4(
          a0, b0[ni], acc[ni], 0, 0, 0, 0x7D7D7D7Du /*A 2^-2*/, 0,
          0x7B7B7B7Bu /*B 2^-4*/);
#pragma unroll
    for (int ni = 0; ni < 4; ++ni)
      acc[ni] = __builtin_amdgcn_mfma_scale_f32_32x32x64_f8f6f4(
          a1, b1[ni], acc[ni], 0, 0, 0, 0x7D7D7D7Du, 0, 0x7B7B7B7Bu);
  }

  // ---- Phase 3: bias + lin + LayerNorm + PReLU -------------------------
  // C/D 32x32 layout: col = lane&31, row = (rg&3) + 8*(rg>>2) + 4*(lane>>5)
  float bb[4], cs[4][9], ci[4][9];
#pragma unroll
  for (int ni = 0; ni < 4; ++ni) {
    const int c = nb + ni * 32 + l31;
    bb[ni] = biases[c];
#pragma unroll
    for (int s = 0; s < 9; ++s) {
      cs[ni][s] = slt[s * N_OUT + c];
      ci[ni][s] = ict[s * N_OUT + c];
    }
  }

#pragma unroll
  for (int rg = 0; rg < 16; ++rg) {
    const int rl = (rg & 3) + 8 * (rg >> 2) + 4 * lh;
    float sx[9], sc[9];
#pragma unroll
    for (int s = 0; s < 9; ++s) {
      sx[s] = seg_lds[rl][s];       // broadcast reads (same addr per half)
      sc[s] = seg_lds[rl][12 + s];
    }
    float ssum = 0.f, qsum = 0.f;
#pragma unroll
    for (int ni = 0; ni < 4; ++ni) {
      float y = acc[ni][rg] + bb[ni];
#pragma unroll
      for (int s = 0; s < 9; ++s) y += sx[s] * cs[ni][s] + sc[s] * ci[ni][s];
      acc[ni][rg] = y;  // keep y in-register until mu/rstd known
      ssum += y;
      qsum += y * y;
    }
#pragma unroll
    for (int off = 16; off > 0; off >>= 1) {  // stays within 32-lane half
      ssum += __shfl_xor(ssum, off);
      qsum += __shfl_xor(qsum, off);
    }
    if (l31 == 0) red[w][rl] = make_float2(ssum, qsum);  // lanes 0 and 32
  }
  __syncthreads();
  if (t < 32) {
    float s = 0.f, q = 0.f;
#pragma unroll
    for (int wv = 0; wv < 8; ++wv) {
      float2 p = red[wv][t];
      s += p.x;
      q += p.y;
    }
    const float mu = s * (1.0f / 1024.0f);
    const float rstd = rsqrtf(q * (1.0f / 1024.0f) - mu * mu + 1e-5f);
    rowstat[t] = make_float2(mu, rstd);
  }
  const float pw = prelu_w[0];
  __syncthreads();
#pragma unroll
  for (int rg = 0; rg < 16; ++rg) {
    const int rl = (rg & 3) + 8 * (rg >> 2) + 4 * lh;
    const float2 ms = rowstat[rl];
    float* orow = out + (r0 + rl) * N_OUT;
#pragma unroll
    for (int ni = 0; ni < 4; ++ni) {
      float z = (acc[ni][rg] - ms.x) * ms.y;
      z = z >= 0.f ? z : pw * z;
      __builtin_nontemporal_store(z, &orow[nb + ni * 32 + l31]);
    }
  }
}

extern "C" void kernel_launch(void* const* d_in, const int* in_sizes, int n_in,
                              void* d_out, int out_size, void* d_ws, size_t ws_size,
                              hipStream_t stream) {
  const float* x = (const float*)d_in[0];
  const float* W = (const float*)d_in[1];
  const float* biases = (const float*)d_in[2];
  const float* slopes = (const float*)d_in[3];
  const float* icpts = (const float*)d_in[4];
  const float* prelu_w = (const float*)d_in[5];
  float* out = (float*)d_out;

  char* ws = (char*)d_ws;
  unsigned char* Wb8 = (unsigned char*)ws;               // 1 MB fp8 16*W
  float* slt = (float*)(ws + (2u << 20));                // 9*1024 fp32
  float* ict = (float*)(ws + (2u << 20) + (64u << 10));  // 9*1024 fp32

  prep_w<<<N_OUT + 64, 256, 0, stream>>>(W, Wb8, slopes, icpts, slt, ict);
  fused<<<BATCHN / 32, 512, 0, stream>>>(x, Wb8, biases, slt, ict, prelu_w, out);
}

// Round 4
// 165.919 us; speedup vs baseline: 1.1097x; 1.1097x over previous
//
#include <hip/hip_runtime.h>
#include <hip/hip_fp8.h>

#define N_IN 1024
#define N_OUT 1024
#define BATCHN 8192

typedef __attribute__((ext_vector_type(4))) int intx4;
typedef __attribute__((ext_vector_type(8))) int intx8;
typedef __attribute__((ext_vector_type(16))) float floatx16;

__device__ __forceinline__ unsigned int f2e4m3(float f) {  // OCP e4m3fn byte
  __hip_fp8_e4m3 v(f);
  return (unsigned int)v.__x;
}
// gelu ~= v * sigmoid(1.702 v) = v * rcp(1 + exp2(-2.4554 v)).
// Max abs err ~0.02 — below the fp8 e4m3 quantization noise of the GEMM path.
__device__ __forceinline__ float gelu_fast(float v) {
  float e = __builtin_amdgcn_exp2f(-2.4554443f * v);
  return v * __builtin_amdgcn_rcpf(1.0f + e);
}

// ---------------------------------------------------------------------------
// Kernel 1: tiny prep.
// blocks [0,1024): W rows -> fp8 e4m3 (x16 scale), written in MFMA-native
//   tiled layout so GEMM B-fragment loads are fully coalesced:
//   for K64-chunk kc and 32-col group g, a 2 KB block holds
//     [sec(0: k bytes lh*32+[0,16), 1: +[16,32))][lane = lh*32 + (col&31)][16B]
//   GEMM reads it as  base + lane*16  (lo)  and  base + 1024 + lane*16  (hi).
// blocks [1024,1088): slopes/intercepts [:,0,:] gather-transpose (s-major).
// ---------------------------------------------------------------------------
__global__ __launch_bounds__(256) void prep_w(const float* __restrict__ W,
                                              unsigned char* __restrict__ Wb8,
                                              const float* __restrict__ slopes,
                                              const float* __restrict__ icpts,
                                              float* __restrict__ slt,
                                              float* __restrict__ ict) {
  const int b = blockIdx.x, t = threadIdx.x;
  if (b < N_OUT) {
    const int o = b;                      // W row == GEMM col
    float4 v = ((const float4*)(W + o * N_IN))[t];  // k bytes 4t..4t+3
    unsigned int pk = f2e4m3(v.x * 16.0f) | (f2e4m3(v.y * 16.0f) << 8) |
                      (f2e4m3(v.z * 16.0f) << 16) | (f2e4m3(v.w * 16.0f) << 24);
    const int kc = t >> 4;                // K64 chunk
    const int lh = (t >> 3) & 1;          // k-half within K64
    const int sec = (t >> 2) & 1;         // lo/hi 16B segment
    const int off = (t & 3) * 4;          // dword within 16B segment
    const int lane = lh * 32 + (o & 31);
    *(unsigned int*)(Wb8 + kc * 65536 + (o >> 5) * 2048 + sec * 1024 +
                     lane * 16 + off) = pk;
  } else {
    const int gb = b - N_OUT;  // 0..63
    const int o = gb * 16 + (t >> 4);
    const int s = t & 15;
    if (s < 9) {
      slt[s * N_OUT + o] = slopes[(long)o * 9216 + s];  // slopes[o][0][s]
      ict[s * N_OUT + o] = icpts[(long)o * 9216 + s];
    }
  }
}

// ---------------------------------------------------------------------------
// Kernel 2: fully fused. 256 blocks x 512 threads (8 waves), 1 block/CU.
// Block owns 32 rows x all 1024 cols.
//   Phase 1: wave w stages rows 4w..4w+3: gelu(x)*4 -> fp8 in LDS
//            (16B-chunk XOR swizzle) + per-row segment stats into LDS.
//   Phase 2: MX-fp8 GEMM. Wave w computes cols [128w,128w+128): A frags from
//            LDS, B frags direct from L2 in the MFMA-native tiled layout
//            (base + lane*16 -> 1 KB contiguous per instruction; 16 lines,
//            every byte used once). No barriers in the K-loop.
//   Phase 3: + bias + rank-18 lin term, full-row LayerNorm via shfl +
//            cross-wave LDS partials, PReLU, nontemporal f32 stores.
// ---------------------------------------------------------------------------
__global__ __launch_bounds__(512) void fused(const float* __restrict__ x,
                                             const unsigned char* __restrict__ Wb8,
                                             const float* __restrict__ biases,
                                             const float* __restrict__ slt,
                                             const float* __restrict__ ict,
                                             const float* __restrict__ prelu_w,
                                             float* __restrict__ out) {
  __shared__ unsigned char lA[32 * 1024];   // 32 KB fp8 A tile (swizzled)
  __shared__ float seg_lds[32][24];         // sx at [0..8], sc at [12..20]
  __shared__ float2 red[8][32];             // per-wave (sum, sumsq) partials
  __shared__ float2 rowstat[32];            // (mu, rstd)

  const int t = threadIdx.x;
  const int lane = t & 63, w = t >> 6;
  const int l31 = lane & 31, lh = lane >> 5;
  const int r0 = blockIdx.x * 32;

  // ---- Phase 1: stage A + segment stats --------------------------------
  for (int jr = 0; jr < 4; ++jr) {
    const int rl = 4 * w + jr;  // local row 0..31
    const float* xr = x + (r0 + rl) * N_IN;
    unsigned int* lrow = (unsigned int*)(lA + rl * 1024);
    const int sw = rl & 7;
    float cum[8], cumx[8], totx = 0.f;
#pragma unroll
    for (int s = 0; s < 8; ++s) { cum[s] = 0.f; cumx[s] = 0.f; }
#pragma unroll
    for (int jc = 0; jc < 4; ++jc) {
      float4 v4 = ((const float4*)xr)[lane + 64 * jc];
      float vs[4] = {v4.x, v4.y, v4.z, v4.w};
      unsigned int pk = 0;
#pragma unroll
      for (int e = 0; e < 4; ++e) {
        float v = vs[e];
        pk |= f2e4m3(gelu_fast(v) * 4.0f) << (8 * e);  // x4 scale
        totx += v;
#pragma unroll
        for (int k = 0; k < 8; ++k) {
          bool m = v >= (-1.0f + (float)(k + 1) * (2.0f / 9.0f));
          cum[k] += m ? 1.0f : 0.0f;
          cumx[k] += m ? v : 0.0f;
        }
      }
      const int d = lane + 64 * jc;  // dword index within row (0..255)
      lrow[(((d >> 2) ^ sw) << 2) | (d & 3)] = pk;
    }
#pragma unroll
    for (int off = 32; off > 0; off >>= 1) {
      totx += __shfl_xor(totx, off);
#pragma unroll
      for (int s = 0; s < 8; ++s) {
        cum[s] += __shfl_xor(cum[s], off);
        cumx[s] += __shfl_xor(cumx[s], off);
      }
    }
    if (lane == 0) {
      seg_lds[rl][0] = totx - cumx[0];
      seg_lds[rl][12] = 1024.f - cum[0];
#pragma unroll
      for (int s = 1; s < 8; ++s) {
        seg_lds[rl][s] = cumx[s - 1] - cumx[s];
        seg_lds[rl][12 + s] = cum[s - 1] - cum[s];
      }
      seg_lds[rl][8] = cumx[7];
      seg_lds[rl][20] = cum[7];
    }
  }
  __syncthreads();

  // ---- Phase 2: GEMM, B direct from L2 (coalesced tiled layout) --------
  const int nb = w * 128;
  floatx16 acc[4] = {};
  const unsigned char* aRow = lA + l31 * 1024;
  const int asw = l31 & 7;
  // base for this wave's 4 col-groups; per (kc, ni): + kc*65536 + ni*2048
  const unsigned char* bBase = Wb8 + (w * 4) * 2048 + lane * 16;

#define LOAD_A(ko, AF)                                                         \
  {                                                                            \
    const int c0 = ((ko) >> 4) + lh * 2;                                       \
    intx4 lo = *(const intx4*)(aRow + ((c0 ^ asw) << 4));                      \
    intx4 hi = *(const intx4*)(aRow + (((c0 + 1) ^ asw) << 4));                \
    AF[0] = lo[0]; AF[1] = lo[1]; AF[2] = lo[2]; AF[3] = lo[3];                \
    AF[4] = hi[0]; AF[5] = hi[1]; AF[6] = hi[2]; AF[7] = hi[3];                \
  }
#define LOAD_B(kc, ni, BF)                                                     \
  {                                                                            \
    const unsigned char* bp = bBase + (kc) * 65536 + (ni) * 2048;              \
    intx4 lo = *(const intx4*)bp;                                              \
    intx4 hi = *(const intx4*)(bp + 1024);                                     \
    BF[0] = lo[0]; BF[1] = lo[1]; BF[2] = lo[2]; BF[3] = lo[3];                \
    BF[4] = hi[0]; BF[5] = hi[1]; BF[6] = hi[2]; BF[7] = hi[3];                \
  }

  for (int kt = 0; kt < 16; kt += 2) {  // pair-unrolled: loads lead MFMAs
    intx8 a0, a1, b0[4], b1[4];
    LOAD_A(kt * 64, a0);
    LOAD_A(kt * 64 + 64, a1);
#pragma unroll
    for (int ni = 0; ni < 4; ++ni) LOAD_B(kt, ni, b0[ni]);
#pragma unroll
    for (int ni = 0; ni < 4; ++ni) LOAD_B(kt + 1, ni, b1[ni]);
    __builtin_amdgcn_s_setprio(1);
#pragma unroll
    for (int ni = 0; ni < 4; ++ni)
      acc[ni] = __builtin_amdgcn_mfma_scale_f32_32x32x64_f8f6f4(
          a0, b0[ni], acc[ni], 0, 0, 0, 0x7D7D7D7Du /*A 2^-2*/, 0,
          0x7B7B7B7Bu /*B 2^-4*/);
#pragma unroll
    for (int ni = 0; ni < 4; ++ni)
      acc[ni] = __builtin_amdgcn_mfma_scale_f32_32x32x64_f8f6f4(
          a1, b1[ni], acc[ni], 0, 0, 0, 0x7D7D7D7Du, 0, 0x7B7B7B7Bu);
    __builtin_amdgcn_s_setprio(0);
  }

  // ---- Phase 3: bias + lin + LayerNorm + PReLU -------------------------
  // C/D 32x32 layout: col = lane&31, row = (rg&3) + 8*(rg>>2) + 4*(lane>>5)
  float bb[4], cs[4][9], ci[4][9];
#pragma unroll
  for (int ni = 0; ni < 4; ++ni) {
    const int c = nb + ni * 32 + l31;
    bb[ni] = biases[c];
#pragma unroll
    for (int s = 0; s < 9; ++s) {
      cs[ni][s] = slt[s * N_OUT + c];
      ci[ni][s] = ict[s * N_OUT + c];
    }
  }

#pragma unroll
  for (int rg = 0; rg < 16; ++rg) {
    const int rl = (rg & 3) + 8 * (rg >> 2) + 4 * lh;
    float sx[9], sc[9];
#pragma unroll
    for (int s = 0; s < 9; ++s) {
      sx[s] = seg_lds[rl][s];       // broadcast reads (same addr per half)
      sc[s] = seg_lds[rl][12 + s];
    }
    float ssum = 0.f, qsum = 0.f;
#pragma unroll
    for (int ni = 0; ni < 4; ++ni) {
      float y = acc[ni][rg] + bb[ni];
#pragma unroll
      for (int s = 0; s < 9; ++s) y += sx[s] * cs[ni][s] + sc[s] * ci[ni][s];
      acc[ni][rg] = y;  // keep y in-register until mu/rstd known
      ssum += y;
      qsum += y * y;
    }
#pragma unroll
    for (int off = 16; off > 0; off >>= 1) {  // stays within 32-lane half
      ssum += __shfl_xor(ssum, off);
      qsum += __shfl_xor(qsum, off);
    }
    if (l31 == 0) red[w][rl] = make_float2(ssum, qsum);  // lanes 0 and 32
  }
  __syncthreads();
  if (t < 32) {
    float s = 0.f, q = 0.f;
#pragma unroll
    for (int wv = 0; wv < 8; ++wv) {
      float2 p = red[wv][t];
      s += p.x;
      q += p.y;
    }
    const float mu = s * (1.0f / 1024.0f);
    const float rstd = rsqrtf(q * (1.0f / 1024.0f) - mu * mu + 1e-5f);
    rowstat[t] = make_float2(mu, rstd);
  }
  const float pw = prelu_w[0];
  __syncthreads();
#pragma unroll
  for (int rg = 0; rg < 16; ++rg) {
    const int rl = (rg & 3) + 8 * (rg >> 2) + 4 * lh;
    const float2 ms = rowstat[rl];
    float* orow = out + (r0 + rl) * N_OUT;
#pragma unroll
    for (int ni = 0; ni < 4; ++ni) {
      float z = (acc[ni][rg] - ms.x) * ms.y;
      z = z >= 0.f ? z : pw * z;
      __builtin_nontemporal_store(z, &orow[nb + ni * 32 + l31]);
    }
  }
}

extern "C" void kernel_launch(void* const* d_in, const int* in_sizes, int n_in,
                              void* d_out, int out_size, void* d_ws, size_t ws_size,
                              hipStream_t stream) {
  const float* x = (const float*)d_in[0];
  const float* W = (const float*)d_in[1];
  const float* biases = (const float*)d_in[2];
  const float* slopes = (const float*)d_in[3];
  const float* icpts = (const float*)d_in[4];
  const float* prelu_w = (const float*)d_in[5];
  float* out = (float*)d_out;

  char* ws = (char*)d_ws;
  unsigned char* Wb8 = (unsigned char*)ws;               // 1 MB fp8 16*W (tiled)
  float* slt = (float*)(ws + (2u << 20));                // 9*1024 fp32
  float* ict = (float*)(ws + (2u << 20) + (64u << 10));  // 9*1024 fp32

  prep_w<<<N_OUT + 64, 256, 0, stream>>>(W, Wb8, slopes, icpts, slt, ict);
  fused<<<BATCHN / 32, 512, 0, stream>>>(x, Wb8, biases, slt, ict, prelu_w, out);
}